// Round 7
// baseline (150.585 us; speedup 1.0000x reference)
//
#include <hip/hip_runtime.h>
#include <stdint.h>

// DCNv2 forward, MI355X — R18: 2 waves/SIMD with unchanged traffic.
//  R13-R17 matrix: barrier type (R14), asm pinning (R15), block TLP w/ B-dup
//  (R16), barrier count 72->10 (R17) ALL lose to R13 (50.6us). Invariant
//  across all five: VALUBusy+MfmaUtil ~32-38% => ~60% SIMD-idle at
//  1 wave/SIMD — any stall idles the SIMD regardless of schedule.
//  R18 = R13 schedule VERBATIM (plain loads, 2-ahead register prefetch,
//  __syncthreads per tile), geometry only: 512 threads / 8 waves, N-split
//  8 x 32 cols, BM=64 kept => B + sampling traffic unchanged, grid 256 =
//  1 block/CU = 2 waves/SIMD. Wave A's gather stall is covered by wave B's
//  bilinear/MFMA issue (m114 mechanism), converging only at the barrier.
//  + bilinear unpack via bf16 lo/hi pair bit-ops (strictly fewer VALU).
//  K0 prep_and_transpose, K1 offset_conv_sk, K2 index_prep unchanged.

#define CIN 256
#define COUT 256
#define HWS 4096      // H*W
#define MTOT 16384    // B*H*W
#define KTOT 2304     // CIN*9
#define SPLITK 8

typedef __attribute__((ext_vector_type(8))) short bf16x8;
typedef __attribute__((ext_vector_type(4))) float f32x4;

__device__ __forceinline__ unsigned short f2bf(float f) {
  unsigned int u = __float_as_uint(f);
  unsigned int r = (u + 0x7fffu + ((u >> 16) & 1u)) >> 16;
  return (unsigned short)r;
}
__device__ __forceinline__ float bf2f(unsigned short u) {
  return __uint_as_float(((unsigned int)u) << 16);
}
// bf16 pair unpack: 1 VALU each (lshl / and) instead of extract+shl.
__device__ __forceinline__ float bflo(unsigned int u) { return __uint_as_float(u << 16); }
__device__ __forceinline__ float bfhi(unsigned int u) { return __uint_as_float(u & 0xffff0000u); }

__device__ __forceinline__ void gload_lds16(const void* g, void* l) {
  __builtin_amdgcn_global_load_lds((const __attribute__((address_space(1))) void*)g,
                                   (__attribute__((address_space(3))) void*)l, 16, 0, 0);
}

// ---------------- K0: fused transpose + weight prep (WB2 frag-block order) ----------------
__global__ __launch_bounds__(256) void prep_and_transpose(const float* __restrict__ x,
                                                          const float* __restrict__ w,
                                                          const float* __restrict__ pw,
                                                          unsigned short* __restrict__ xt,
                                                          unsigned short* __restrict__ WB,
                                                          unsigned short* __restrict__ PWs,
                                                          unsigned short* __restrict__ zerop) {
  __shared__ float tile[32][33];
  int bid = blockIdx.x;
  if (bid < 4096) {
    int b = bid >> 10;
    int rest = bid & 1023;
    int hw0 = (rest & 127) * 32;
    int c0 = ((rest >> 7) & 7) * 32;
    int tx = threadIdx.x & 31, ty = threadIdx.x >> 5;
    for (int i = ty; i < 32; i += 8)
      tile[i][tx] = x[(size_t)(b * CIN + c0 + i) * HWS + hw0 + tx];
    __syncthreads();
    for (int r = ty; r < 32; r += 8)
      xt[(size_t)(b * HWS + hw0 + r) * CIN + c0 + tx] = f2bf(tile[tx][r]);
  } else {
    int idx = (bid - 4096) * 256 + threadIdx.x;
    if (idx < 512)
      *(uint4*)(zerop + idx * 8) = make_uint4(0, 0, 0, 0);
    if (idx < KTOT * COUT) {
      // WB2[t][j][quad][row][8]: f = (((t*16+j)*4+quad)*16+row)*8+e
      int f = idx;
      int e = f & 7;
      int row = (f >> 3) & 15;
      int quad = (f >> 7) & 3;
      int j = (f >> 9) & 15;
      int t = f >> 13;                 // 0..71
      int kk = t * 32 + quad * 8 + e;
      int o = j * 16 + row;
      int k = kk >> 8, c = kk & 255;
      WB[f] = f2bf(w[o * KTOT + c * 9 + k]);
    } else {
      int f2 = idx - KTOT * COUT;   // < 2304*32
      int t_ = f2 & 7;
      int rest = f2 >> 3;
      int j = rest & 31;
      int kk = (rest >> 5) * 8 + t_;
      int k = kk >> 8, c = kk & 255;
      float v = (j < 27) ? pw[j * KTOT + c * 9 + k] : 0.0f;
      PWs[f2] = f2bf(v);
    }
  }
}

// ---------------- K1: offset conv, split-K, BM=64 ----------------
__global__ __launch_bounds__(256) void offset_conv_sk(const unsigned short* __restrict__ xt,
                                                      const unsigned short* __restrict__ PWs,
                                                      const unsigned short* __restrict__ zerop,
                                                      float* __restrict__ Pbuf) {
  __shared__ unsigned short Al[64 * 32];   // 4 KB
  __shared__ unsigned short Bl[1024];      // 2 KB
  int tid = threadIdx.x;
  int lane = tid & 63, wv = tid >> 6;
  int mt = (blockIdx.x & 7) * 32 + (blockIdx.x >> 3);   // XCD swizzle
  int m0 = mt * 64;
  int s = blockIdx.y;
  int b = m0 >> 12;
  int hw0 = m0 & 4095;
  f32x4 acc[2] = {};

  for (int tt = 0; tt < 72 / SPLITK; ++tt) {
    int t = s * (72 / SPLITK) + tt;
    int k = t >> 3, c0 = (t & 7) * 32;
    int dyk = k / 3 - 1;
    int dxk = k % 3 - 1;
    __syncthreads();
    if (tid < 128)
      gload_lds16(PWs + (size_t)t * 1024 + tid * 8, &Bl[tid * 8]);
    {
      int r = tid >> 2;
      int hw = hw0 + r;
      int h = hw >> 6, wwp = hw & 63;
      int y = h + dyk, xx = wwp + dxk;
      bool valid = ((unsigned)y < 64u) && ((unsigned)xx < 64u);
      const unsigned short* src = valid
          ? xt + ((size_t)((b << 12) + (y << 6) + xx) << 8) + c0 + (tid & 3) * 8
          : zerop;
      gload_lds16(src, &Al[tid * 8]);
    }
    __syncthreads();
    int row = lane & 15, quad = lane >> 4;
    bf16x8 af = *(const bf16x8*)&Al[(wv * 16 + row) * 32 + quad * 8];
    for (int j = 0; j < 2; ++j) {
      bf16x8 bfr = *(const bf16x8*)&Bl[(quad * 32 + j * 16 + row) * 8];
      acc[j] = __builtin_amdgcn_mfma_f32_16x16x32_bf16(af, bfr, acc[j], 0, 0, 0);
    }
  }

  int row = lane & 15, quad = lane >> 4;
  for (int j = 0; j < 2; ++j) {
    int n = j * 16 + row;
    for (int r_ = 0; r_ < 4; ++r_) {
      int m = m0 + wv * 16 + quad * 4 + r_;
      Pbuf[((size_t)s * MTOT + m) * 32 + n] = acc[j][r_];
    }
  }
}

// ---------------- K2: index prep — reduce Pbuf, compute corner idx + weights ----------------
// DIW layout: per (m, k): { int4 dI (elem offsets), float4 dW (corner weights*mask) }
__global__ __launch_bounds__(256) void index_prep(const float* __restrict__ Pbuf,
                                                  const float* __restrict__ p_bias,
                                                  int4* __restrict__ DIW) {
  int gid = blockIdx.x * 256 + threadIdx.x;   // 0..147455 == 16384*9
  int m = gid / 9;
  int k = gid - m * 9;

  float dy = p_bias[2 * k];
  float dx = p_bias[2 * k + 1];
  float mv = p_bias[18 + k];
#pragma unroll
  for (int s = 0; s < SPLITK; ++s) {
    const float* p = Pbuf + ((size_t)s * MTOT + m) * 32;
    dy += p[2 * k];
    dx += p[2 * k + 1];
    mv += p[18 + k];
  }
  float mk = 1.0f / (1.0f + __expf(-mv));

  int hw = m & 4095, h = hw >> 6, ww = hw & 63;
  float py = (float)(h - 1 + k / 3) + dy;
  float px = (float)(ww - 1 + k % 3) + dx;
  float y0f = floorf(py), x0f = floorf(px);
  float ay = py - y0f, ax = px - x0f;
  int y0 = (int)y0f, x0 = (int)x0f;

  float w00 = (1.f - ay) * (1.f - ax) * mk;
  float w01 = (1.f - ay) * ax * mk;
  float w10 = ay * (1.f - ax) * mk;
  float w11 = ay * ax * mk;

  float vy0 = ((unsigned)y0 < 64u) ? 1.f : 0.f;
  float vy1 = ((unsigned)(y0 + 1) < 64u) ? 1.f : 0.f;
  float vx0 = ((unsigned)x0 < 64u) ? 1.f : 0.f;
  float vx1 = ((unsigned)(x0 + 1) < 64u) ? 1.f : 0.f;
  w00 *= vy0 * vx0; w01 *= vy0 * vx1; w10 *= vy1 * vx0; w11 *= vy1 * vx1;

  int yc0 = min(max(y0, 0), 63), yc1 = min(max(y0 + 1, 0), 63);
  int xc0 = min(max(x0, 0), 63), xc1 = min(max(x0 + 1, 0), 63);

  DIW[(size_t)gid * 2] = make_int4((yc0 * 64 + xc0) * 256, (yc0 * 64 + xc1) * 256,
                                   (yc1 * 64 + xc0) * 256, (yc1 * 64 + xc1) * 256);
  float4 w4 = make_float4(w00, w01, w10, w11);
  ((float4*)DIW)[(size_t)gid * 2 + 1] = w4;
}

// ---------------- K3: fused sample + GEMM, 8 waves / 2 per SIMD ----------------
// Block: 64 m-rows x 256 cols, 512 threads. Wave w: 64 rows x 32 cols
// (n = w*32..w*32+32). Sampler: 8 threads/row x 4 ch. R13 schedule verbatim.
__device__ __forceinline__ void bilin4p(const uint2 c00, const uint2 c01,
                                        const uint2 c10, const uint2 c11,
                                        const float4 w4, unsigned short* dst) {
  float v0 = w4.x * bflo(c00.x) + w4.y * bflo(c01.x) + w4.z * bflo(c10.x) + w4.w * bflo(c11.x);
  float v1 = w4.x * bfhi(c00.x) + w4.y * bfhi(c01.x) + w4.z * bfhi(c10.x) + w4.w * bfhi(c11.x);
  float v2 = w4.x * bflo(c00.y) + w4.y * bflo(c01.y) + w4.z * bflo(c10.y) + w4.w * bflo(c11.y);
  float v3 = w4.x * bfhi(c00.y) + w4.y * bfhi(c01.y) + w4.z * bfhi(c10.y) + w4.w * bfhi(c11.y);
  ushort4 o;
  o.x = f2bf(v0); o.y = f2bf(v1); o.z = f2bf(v2); o.w = f2bf(v3);
  *(ushort4*)dst = o;
}

#define MFMA8(A0, A1, A2_, A3, B0, B1)                                                   \
  acc[0][0] = __builtin_amdgcn_mfma_f32_16x16x32_bf16(A0, B0, acc[0][0], 0, 0, 0);       \
  acc[0][1] = __builtin_amdgcn_mfma_f32_16x16x32_bf16(A0, B1, acc[0][1], 0, 0, 0);       \
  acc[1][0] = __builtin_amdgcn_mfma_f32_16x16x32_bf16(A1, B0, acc[1][0], 0, 0, 0);       \
  acc[1][1] = __builtin_amdgcn_mfma_f32_16x16x32_bf16(A1, B1, acc[1][1], 0, 0, 0);       \
  acc[2][0] = __builtin_amdgcn_mfma_f32_16x16x32_bf16(A2_, B0, acc[2][0], 0, 0, 0);      \
  acc[2][1] = __builtin_amdgcn_mfma_f32_16x16x32_bf16(A2_, B1, acc[2][1], 0, 0, 0);      \
  acc[3][0] = __builtin_amdgcn_mfma_f32_16x16x32_bf16(A3, B0, acc[3][0], 0, 0, 0);       \
  acc[3][1] = __builtin_amdgcn_mfma_f32_16x16x32_bf16(A3, B1, acc[3][1], 0, 0, 0);

// Tile body T (PAR = T&1 literal). R13 order:
//  a) plain-load gathers(T+2) [dI4 advanced at (T+2)&7==0, one tap AHEAD of dW4]
//  b) plain-load B(T+1) -> BN*
//  c) ds_read A-frags(T)
//  d) bilin4p(T+1) -> As[PAR^1]  [dW4 advanced at (T+1)&7==0]
//  e) 8 MFMA
//  f) __syncthreads
#define FITER(T, PAR, BC0, BC1, BN0, BN1)                                                \
  {                                                                                      \
    if ((T) <= 69) {                                                                     \
      if ((((T) + 2) & 7) == 0) dI4 = Tbl[r][((T) + 2) >> 3][0];                         \
      int cq = (((T) + 2) & 7) * 32 + qo;                                                \
      g00 = *(const uint2*)(xtb + dI4.x + cq);                                           \
      g01 = *(const uint2*)(xtb + dI4.y + cq);                                           \
      g10 = *(const uint2*)(xtb + dI4.z + cq);                                           \
      g11 = *(const uint2*)(xtb + dI4.w + cq);                                           \
    }                                                                                    \
    if ((T) <= 70) {                                                                     \
      const unsigned short* bt_ = bpb + (size_t)((T) + 1) * 8192;                        \
      BN0 = *(const bf16x8*)(bt_);                                                       \
      BN1 = *(const bf16x8*)(bt_ + 512);                                                 \
    }                                                                                    \
    afr0 = *(const bf16x8*)&As[PAR][row][quad * 8];                                      \
    afr1 = *(const bf16x8*)&As[PAR][16 + row][quad * 8];                                 \
    afr2 = *(const bf16x8*)&As[PAR][32 + row][quad * 8];                                 \
    afr3 = *(const bf16x8*)&As[PAR][48 + row][quad * 8];                                 \
    if ((T) <= 70) {                                                                     \
      if ((((T) + 1) & 7) == 0) dW4 = *(float4*)&Tbl[r][((T) + 1) >> 3][1];              \
      bilin4p(gp0, gp1, gp2, gp3, dW4, &As[PAR ^ 1][r][qo]);                             \
    }                                                                                    \
    MFMA8(afr0, afr1, afr2, afr3, BC0, BC1)                                              \
    __syncthreads();                                                                     \
  }

__global__ __launch_bounds__(512, 2) void fused_gemm(const unsigned short* __restrict__ xt,
                                                     const int4* __restrict__ DIW,
                                                     const unsigned short* __restrict__ WB,
                                                     const float* __restrict__ bias,
                                                     float* __restrict__ out) {
  __shared__ unsigned short As[2][64][40];   // 10,240 B (padded +8)
  __shared__ int4 Tbl[64][9][2];             // 18,432 B [r][tap]{dI, dW}

  int tid = threadIdx.x;
  int lane = tid & 63, wv = tid >> 6;        // 8 waves
  // XCD-chunked swizzle: XCD x gets 32 consecutive m-tiles (2048 m-rows).
  int mt = (blockIdx.x & 7) * 32 + (blockIdx.x >> 3);
  int mb = mt * 64;
  int b = mb >> 12;
  int hw0 = mb & 4095;
  const unsigned short* xtb = xt + ((size_t)b << 20);

  // stage index/weight table for this block's 64 rows (1152 int4)
  {
    const int4* src = DIW + (size_t)mb * 18;
    int4* dst = (int4*)Tbl;
    for (int i = tid; i < 1152; i += 512)
      gload_lds16(src + i, dst + i);
  }
  __syncthreads();   // drains global_load_lds staging — once

  int r = tid >> 3;        // sampler row 0..63 (8 threads/row)
  int qo = (tid & 7) * 4;  // sampler channel sub-block (4 ch, 8 B)

  int4 dI4 = Tbl[r][0][0];
  float4 dW4 = *(float4*)&Tbl[r][0][1];

  int row = lane & 15, quad = lane >> 4;
  const unsigned short* bpb = WB + (size_t)(wv * 2) * 512 + quad * 128 + row * 8;

  f32x4 acc[4][2] = {};
  uint2 g00, g01, g10, g11;            // in-flight gathers (next-next tile)
  uint2 gp0, gp1, gp2, gp3;            // gathers pending consumption (next tile)
  bf16x8 bA0, bA1, bB0, bB1;
  bf16x8 afr0, afr1, afr2, afr3;

  // ---- prologue: sample tile 0 directly, load B(0), issue gathers(1) ----
  {
    g00 = *(const uint2*)(xtb + dI4.x + qo);
    g01 = *(const uint2*)(xtb + dI4.y + qo);
    g10 = *(const uint2*)(xtb + dI4.z + qo);
    g11 = *(const uint2*)(xtb + dI4.w + qo);
    bA0 = *(const bf16x8*)(bpb);
    bA1 = *(const bf16x8*)(bpb + 512);
    bilin4p(g00, g01, g10, g11, dW4, &As[0][r][qo]);
    // gathers for tile 1 (tap 0, c0 = 32)
    g00 = *(const uint2*)(xtb + dI4.x + 32 + qo);
    g01 = *(const uint2*)(xtb + dI4.y + 32 + qo);
    g10 = *(const uint2*)(xtb + dI4.z + 32 + qo);
    g11 = *(const uint2*)(xtb + dI4.w + 32 + qo);
  }
  __syncthreads();

#pragma unroll 1
  for (int t = 0; t < 72; t += 2) {
    gp0 = g00; gp1 = g01; gp2 = g10; gp3 = g11;
    FITER(t, 0, bA0, bA1, bB0, bB1)
    gp0 = g00; gp1 = g01; gp2 = g10; gp3 = g11;
    FITER(t + 1, 1, bB0, bB1, bA0, bA1)
  }

  // ---- epilogue: add bias, store NCHW ----
#pragma unroll
  for (int j = 0; j < 2; ++j) {
    int o = wv * 32 + j * 16 + row;
    float bo = bias[o];
#pragma unroll
    for (int i = 0; i < 4; ++i) {
      int hw = hw0 + i * 16 + quad * 4;
      float4 v;
      v.x = acc[i][j][0] + bo;
      v.y = acc[i][j][1] + bo;
      v.z = acc[i][j][2] + bo;
      v.w = acc[i][j][3] + bo;
      *(float4*)(out + (((size_t)(b * COUT + o)) << 12) + hw) = v;
    }
  }
}

// ---------------- launch ----------------
extern "C" void kernel_launch(void* const* d_in, const int* in_sizes, int n_in,
                              void* d_out, int out_size, void* d_ws, size_t ws_size,
                              hipStream_t stream) {
  const float* x        = (const float*)d_in[0];
  const float* weight   = (const float*)d_in[1];
  const float* bias     = (const float*)d_in[2];
  const float* p_weight = (const float*)d_in[3];
  const float* p_bias   = (const float*)d_in[4];
  float* out = (float*)d_out;
  char* ws = (char*)d_ws;

  // workspace layout (bytes); total ~31 MB
  const size_t OFF_XT   = 0;                          //  8,388,608  bf16 NHWC x
  const size_t OFF_WB   = OFF_XT + 8388608;           //  1,179,648  bf16 WB2
  const size_t OFF_PW   = OFF_WB + 1179648;           //    147,456  bf16
  const size_t OFF_P    = OFF_PW + 147456;            // 16,777,216  fp32 partials
  const size_t OFF_ZP   = OFF_P + 16777216;           //      8,192  zeropage
  const size_t OFF_DIW  = OFF_ZP + 8192;              //  4,718,592  idx/weight table

  unsigned short* xt    = (unsigned short*)(ws + OFF_XT);
  unsigned short* WB    = (unsigned short*)(ws + OFF_WB);
  unsigned short* PWs   = (unsigned short*)(ws + OFF_PW);
  float* Pbuf           = (float*)(ws + OFF_P);
  unsigned short* zerop = (unsigned short*)(ws + OFF_ZP);
  int4* DIW             = (int4*)(ws + OFF_DIW);

  prep_and_transpose<<<4096 + 2592, 256, 0, stream>>>(x, weight, p_weight, xt, WB, PWs, zerop);
  offset_conv_sk<<<dim3(MTOT / 64, SPLITK), 256, 0, stream>>>(xt, PWs, zerop, Pbuf);
  index_prep<<<576, 256, 0, stream>>>(Pbuf, p_bias, DIW);
  fused_gemm<<<256, 512, 0, stream>>>(xt, DIW, WB, bias, out);
}

// Round 8
// 133.659 us; speedup vs baseline: 1.1266x; 1.1266x over previous
//
#include <hip/hip_runtime.h>
#include <stdint.h>

// DCNv2 forward, MI355X — R19: the untested cell — asm-pinned loads +
//  COUNTED vmcnt + lgkm-only barrier (AITER/T4 discipline, vmcnt never 0).
//  R13-R18 matrix: every variant was either (a) prefetch collapsed by the
//  compiler (R13/14/16/18: VGPR 60-84, loads sunk to consumers => serial L2
//  latency per tile) or (b) pinned but vmcnt(0)-drained at each barrier
//  (R15/R17). R19: gathers+B issued via volatile asm (cannot sink), waits
//  are counted immediates (steady state: vmcnt(8) before bilin, vmcnt(6)
//  before MFMA), barrier is lgkmcnt(0)+s_barrier only => 6-12 loads in
//  flight across every barrier. Register rotation via two named sets
//  (even/odd tiles) — NO copies of un-waited load dests (v_mov of an
//  unwaited VMEM dest is undefined). sched_barrier(0) after each wait
//  (rule #18). Tail peeled: T=70 vmcnt(4)/(2), T=71 vmcnt(0).
//  Geometry = R18 (512 thr, 8 waves, BM=64, grid 256, traffic-minimal).
//  K0 prep_and_transpose, K1 offset_conv_sk, K2 index_prep unchanged.

#define CIN 256
#define COUT 256
#define HWS 4096      // H*W
#define MTOT 16384    // B*H*W
#define KTOT 2304     // CIN*9
#define SPLITK 8

typedef __attribute__((ext_vector_type(8))) short bf16x8;
typedef __attribute__((ext_vector_type(4))) float f32x4;

__device__ __forceinline__ unsigned short f2bf(float f) {
  unsigned int u = __float_as_uint(f);
  unsigned int r = (u + 0x7fffu + ((u >> 16) & 1u)) >> 16;
  return (unsigned short)r;
}
__device__ __forceinline__ float bf2f(unsigned short u) {
  return __uint_as_float(((unsigned int)u) << 16);
}
// bf16 pair unpack: 1 VALU each.
__device__ __forceinline__ float bflo(unsigned int u) { return __uint_as_float(u << 16); }
__device__ __forceinline__ float bfhi(unsigned int u) { return __uint_as_float(u & 0xffff0000u); }

__device__ __forceinline__ void gload_lds16(const void* g, void* l) {
  __builtin_amdgcn_global_load_lds((const __attribute__((address_space(1))) void*)g,
                                   (__attribute__((address_space(3))) void*)l, 16, 0, 0);
}

// Issue-pinned loads. Completion is NOT compiler-tracked: consumption must
// follow a manual counted s_waitcnt + sched_barrier.
#define GLOAD8(D, P)  asm volatile("global_load_dwordx2 %0, %1, off" : "=v"(D) : "v"(P))
#define GLOAD16(D, P) asm volatile("global_load_dwordx4 %0, %1, off" : "=v"(D) : "v"(P))
#define WAITVM(N)                                            \
  {                                                          \
    asm volatile("s_waitcnt vmcnt(" #N ")" ::: "memory");    \
    __builtin_amdgcn_sched_barrier(0);                       \
  }
#define BARRIER_LGKM                                                  \
  { asm volatile("s_waitcnt lgkmcnt(0)\n\ts_barrier" ::: "memory"); }

// ---------------- K0: fused transpose + weight prep (WB2 frag-block order) ----------------
__global__ __launch_bounds__(256) void prep_and_transpose(const float* __restrict__ x,
                                                          const float* __restrict__ w,
                                                          const float* __restrict__ pw,
                                                          unsigned short* __restrict__ xt,
                                                          unsigned short* __restrict__ WB,
                                                          unsigned short* __restrict__ PWs,
                                                          unsigned short* __restrict__ zerop) {
  __shared__ float tile[32][33];
  int bid = blockIdx.x;
  if (bid < 4096) {
    int b = bid >> 10;
    int rest = bid & 1023;
    int hw0 = (rest & 127) * 32;
    int c0 = ((rest >> 7) & 7) * 32;
    int tx = threadIdx.x & 31, ty = threadIdx.x >> 5;
    for (int i = ty; i < 32; i += 8)
      tile[i][tx] = x[(size_t)(b * CIN + c0 + i) * HWS + hw0 + tx];
    __syncthreads();
    for (int r = ty; r < 32; r += 8)
      xt[(size_t)(b * HWS + hw0 + r) * CIN + c0 + tx] = f2bf(tile[tx][r]);
  } else {
    int idx = (bid - 4096) * 256 + threadIdx.x;
    if (idx < 512)
      *(uint4*)(zerop + idx * 8) = make_uint4(0, 0, 0, 0);
    if (idx < KTOT * COUT) {
      // WB2[t][j][quad][row][8]: f = (((t*16+j)*4+quad)*16+row)*8+e
      int f = idx;
      int e = f & 7;
      int row = (f >> 3) & 15;
      int quad = (f >> 7) & 3;
      int j = (f >> 9) & 15;
      int t = f >> 13;                 // 0..71
      int kk = t * 32 + quad * 8 + e;
      int o = j * 16 + row;
      int k = kk >> 8, c = kk & 255;
      WB[f] = f2bf(w[o * KTOT + c * 9 + k]);
    } else {
      int f2 = idx - KTOT * COUT;   // < 2304*32
      int t_ = f2 & 7;
      int rest = f2 >> 3;
      int j = rest & 31;
      int kk = (rest >> 5) * 8 + t_;
      int k = kk >> 8, c = kk & 255;
      float v = (j < 27) ? pw[j * KTOT + c * 9 + k] : 0.0f;
      PWs[f2] = f2bf(v);
    }
  }
}

// ---------------- K1: offset conv, split-K, BM=64 ----------------
__global__ __launch_bounds__(256) void offset_conv_sk(const unsigned short* __restrict__ xt,
                                                      const unsigned short* __restrict__ PWs,
                                                      const unsigned short* __restrict__ zerop,
                                                      float* __restrict__ Pbuf) {
  __shared__ unsigned short Al[64 * 32];   // 4 KB
  __shared__ unsigned short Bl[1024];      // 2 KB
  int tid = threadIdx.x;
  int lane = tid & 63, wv = tid >> 6;
  int mt = (blockIdx.x & 7) * 32 + (blockIdx.x >> 3);   // XCD swizzle
  int m0 = mt * 64;
  int s = blockIdx.y;
  int b = m0 >> 12;
  int hw0 = m0 & 4095;
  f32x4 acc[2] = {};

  for (int tt = 0; tt < 72 / SPLITK; ++tt) {
    int t = s * (72 / SPLITK) + tt;
    int k = t >> 3, c0 = (t & 7) * 32;
    int dyk = k / 3 - 1;
    int dxk = k % 3 - 1;
    __syncthreads();
    if (tid < 128)
      gload_lds16(PWs + (size_t)t * 1024 + tid * 8, &Bl[tid * 8]);
    {
      int r = tid >> 2;
      int hw = hw0 + r;
      int h = hw >> 6, wwp = hw & 63;
      int y = h + dyk, xx = wwp + dxk;
      bool valid = ((unsigned)y < 64u) && ((unsigned)xx < 64u);
      const unsigned short* src = valid
          ? xt + ((size_t)((b << 12) + (y << 6) + xx) << 8) + c0 + (tid & 3) * 8
          : zerop;
      gload_lds16(src, &Al[tid * 8]);
    }
    __syncthreads();
    int row = lane & 15, quad = lane >> 4;
    bf16x8 af = *(const bf16x8*)&Al[(wv * 16 + row) * 32 + quad * 8];
    for (int j = 0; j < 2; ++j) {
      bf16x8 bfr = *(const bf16x8*)&Bl[(quad * 32 + j * 16 + row) * 8];
      acc[j] = __builtin_amdgcn_mfma_f32_16x16x32_bf16(af, bfr, acc[j], 0, 0, 0);
    }
  }

  int row = lane & 15, quad = lane >> 4;
  for (int j = 0; j < 2; ++j) {
    int n = j * 16 + row;
    for (int r_ = 0; r_ < 4; ++r_) {
      int m = m0 + wv * 16 + quad * 4 + r_;
      Pbuf[((size_t)s * MTOT + m) * 32 + n] = acc[j][r_];
    }
  }
}

// ---------------- K2: index prep — reduce Pbuf, compute corner idx + weights ----------------
__global__ __launch_bounds__(256) void index_prep(const float* __restrict__ Pbuf,
                                                  const float* __restrict__ p_bias,
                                                  int4* __restrict__ DIW) {
  int gid = blockIdx.x * 256 + threadIdx.x;   // 0..147455 == 16384*9
  int m = gid / 9;
  int k = gid - m * 9;

  float dy = p_bias[2 * k];
  float dx = p_bias[2 * k + 1];
  float mv = p_bias[18 + k];
#pragma unroll
  for (int s = 0; s < SPLITK; ++s) {
    const float* p = Pbuf + ((size_t)s * MTOT + m) * 32;
    dy += p[2 * k];
    dx += p[2 * k + 1];
    mv += p[18 + k];
  }
  float mk = 1.0f / (1.0f + __expf(-mv));

  int hw = m & 4095, h = hw >> 6, ww = hw & 63;
  float py = (float)(h - 1 + k / 3) + dy;
  float px = (float)(ww - 1 + k % 3) + dx;
  float y0f = floorf(py), x0f = floorf(px);
  float ay = py - y0f, ax = px - x0f;
  int y0 = (int)y0f, x0 = (int)x0f;

  float w00 = (1.f - ay) * (1.f - ax) * mk;
  float w01 = (1.f - ay) * ax * mk;
  float w10 = ay * (1.f - ax) * mk;
  float w11 = ay * ax * mk;

  float vy0 = ((unsigned)y0 < 64u) ? 1.f : 0.f;
  float vy1 = ((unsigned)(y0 + 1) < 64u) ? 1.f : 0.f;
  float vx0 = ((unsigned)x0 < 64u) ? 1.f : 0.f;
  float vx1 = ((unsigned)(x0 + 1) < 64u) ? 1.f : 0.f;
  w00 *= vy0 * vx0; w01 *= vy0 * vx1; w10 *= vy1 * vx0; w11 *= vy1 * vx1;

  int yc0 = min(max(y0, 0), 63), yc1 = min(max(y0 + 1, 0), 63);
  int xc0 = min(max(x0, 0), 63), xc1 = min(max(x0 + 1, 0), 63);

  DIW[(size_t)gid * 2] = make_int4((yc0 * 64 + xc0) * 256, (yc0 * 64 + xc1) * 256,
                                   (yc1 * 64 + xc0) * 256, (yc1 * 64 + xc1) * 256);
  float4 w4 = make_float4(w00, w01, w10, w11);
  ((float4*)DIW)[(size_t)gid * 2 + 1] = w4;
}

// ---------------- K3: fused sample + GEMM — counted-vmcnt pipeline ----------------
// 512 threads / 8 waves, BM=64, N-split 8 x 32 cols. Per steady tile T:
//  issue G(T+2) [4 asm dwordx2] -> alternating set; issue B(T+1) [2 asm
//  dwordx4] -> alternating set; ds_read A(T); vmcnt(8)+fence; bilin(T+1)
//  -> As[PAR^1]; vmcnt(6)+fence; 8 MFMA; lgkm-barrier.
__device__ __forceinline__ void bilin4p(const uint2 c00, const uint2 c01,
                                        const uint2 c10, const uint2 c11,
                                        const float4 w4, unsigned short* dst) {
  float v0 = w4.x * bflo(c00.x) + w4.y * bflo(c01.x) + w4.z * bflo(c10.x) + w4.w * bflo(c11.x);
  float v1 = w4.x * bfhi(c00.x) + w4.y * bfhi(c01.x) + w4.z * bfhi(c10.x) + w4.w * bfhi(c11.x);
  float v2 = w4.x * bflo(c00.y) + w4.y * bflo(c01.y) + w4.z * bflo(c10.y) + w4.w * bflo(c11.y);
  float v3 = w4.x * bfhi(c00.y) + w4.y * bfhi(c01.y) + w4.z * bfhi(c10.y) + w4.w * bfhi(c11.y);
  ushort4 o;
  o.x = f2bf(v0); o.y = f2bf(v1); o.z = f2bf(v2); o.w = f2bf(v3);
  *(ushort4*)dst = o;
}

#define MFMA8(A0, A1, A2_, A3, B0, B1)                                                   \
  acc[0][0] = __builtin_amdgcn_mfma_f32_16x16x32_bf16(A0, B0, acc[0][0], 0, 0, 0);       \
  acc[0][1] = __builtin_amdgcn_mfma_f32_16x16x32_bf16(A0, B1, acc[0][1], 0, 0, 0);       \
  acc[1][0] = __builtin_amdgcn_mfma_f32_16x16x32_bf16(A1, B0, acc[1][0], 0, 0, 0);       \
  acc[1][1] = __builtin_amdgcn_mfma_f32_16x16x32_bf16(A1, B1, acc[1][1], 0, 0, 0);       \
  acc[2][0] = __builtin_amdgcn_mfma_f32_16x16x32_bf16(A2_, B0, acc[2][0], 0, 0, 0);      \
  acc[2][1] = __builtin_amdgcn_mfma_f32_16x16x32_bf16(A2_, B1, acc[2][1], 0, 0, 0);      \
  acc[3][0] = __builtin_amdgcn_mfma_f32_16x16x32_bf16(A3, B0, acc[3][0], 0, 0, 0);       \
  acc[3][1] = __builtin_amdgcn_mfma_f32_16x16x32_bf16(A3, B1, acc[3][1], 0, 0, 0);

// Steady tile: GI* = set receiving G(T+2); GC* = set holding G(T+1) (consumed
// by bilin). BN* receives B(T+1); BC* holds B(T) (consumed by MFMA).
#define FITER_S(T, PAR, GI0, GI1, GI2, GI3, GC0, GC1, GC2, GC3, BC0, BC1, BN0, BN1)      \
  {                                                                                      \
    if ((((T) + 2) & 7) == 0) dI4 = Tbl[r][((T) + 2) >> 3][0];                           \
    int cq = (((T) + 2) & 7) * 32 + qo;                                                  \
    GLOAD8(GI0, xtb + dI4.x + cq);                                                       \
    GLOAD8(GI1, xtb + dI4.y + cq);                                                       \
    GLOAD8(GI2, xtb + dI4.z + cq);                                                       \
    GLOAD8(GI3, xtb + dI4.w + cq);                                                       \
    const unsigned short* bt_ = bpb + (size_t)((T) + 1) * 8192;                          \
    GLOAD16(BN0, bt_);                                                                   \
    GLOAD16(BN1, bt_ + 512);                                                             \
    afr0 = *(const bf16x8*)&As[PAR][row][quad * 8];                                      \
    afr1 = *(const bf16x8*)&As[PAR][16 + row][quad * 8];                                 \
    afr2 = *(const bf16x8*)&As[PAR][32 + row][quad * 8];                                 \
    afr3 = *(const bf16x8*)&As[PAR][48 + row][quad * 8];                                 \
    if ((((T) + 1) & 7) == 0) dW4 = *(float4*)&Tbl[r][((T) + 1) >> 3][1];                \
    WAITVM(8)                                                                            \
    bilin4p(GC0, GC1, GC2, GC3, dW4, &As[PAR ^ 1][r][qo]);                               \
    WAITVM(6)                                                                            \
    MFMA8(afr0, afr1, afr2, afr3, BC0, BC1)                                              \
    BARRIER_LGKM                                                                         \
  }

__global__ __launch_bounds__(512, 2) void fused_gemm(const unsigned short* __restrict__ xt,
                                                     const int4* __restrict__ DIW,
                                                     const unsigned short* __restrict__ WB,
                                                     const float* __restrict__ bias,
                                                     float* __restrict__ out) {
  __shared__ unsigned short As[2][64][40];   // 10,240 B (padded +8)
  __shared__ int4 Tbl[64][9][2];             // 18,432 B [r][tap]{dI, dW}

  int tid = threadIdx.x;
  int lane = tid & 63, wv = tid >> 6;        // 8 waves
  int mt = (blockIdx.x & 7) * 32 + (blockIdx.x >> 3);   // XCD-chunked swizzle
  int mb = mt * 64;
  int b = mb >> 12;
  int hw0 = mb & 4095;
  const unsigned short* xtb = xt + ((size_t)b << 20);

  // stage index/weight table (1152 int4) — full drain BEFORE any asm loads
  {
    const int4* src = DIW + (size_t)mb * 18;
    int4* dst = (int4*)Tbl;
    for (int i = tid; i < 1152; i += 512)
      gload_lds16(src + i, dst + i);
  }
  __syncthreads();

  int r = tid >> 3;        // sampler row 0..63 (8 threads/row)
  int qo = (tid & 7) * 4;  // sampler channel sub-block (4 ch, 8 B)

  int4 dI4 = Tbl[r][0][0];
  float4 dW4 = *(float4*)&Tbl[r][0][1];

  int row = lane & 15, quad = lane >> 4;
  const unsigned short* bpb = WB + (size_t)(wv * 2) * 512 + quad * 128 + row * 8;

  f32x4 acc[4][2] = {};
  uint2 gA0, gA1, gA2, gA3;            // even-issue gather set
  uint2 gB0, gB1, gB2, gB3;            // odd-issue gather set
  bf16x8 bA0, bA1, bB0, bB1;
  bf16x8 afr0, afr1, afr2, afr3;

  // ---- prologue ----
  {
    // tile 0 via compiler loads (auto-waited), bilin -> As[0]
    uint2 p00 = *(const uint2*)(xtb + dI4.x + qo);
    uint2 p01 = *(const uint2*)(xtb + dI4.y + qo);
    uint2 p10 = *(const uint2*)(xtb + dI4.z + qo);
    uint2 p11 = *(const uint2*)(xtb + dI4.w + qo);
    bilin4p(p00, p01, p10, p11, dW4, &As[0][r][qo]);
    // pinned issues: G(1) -> gB set (tap 0, c0=32), then B(0) -> bA set
    GLOAD8(gB0, xtb + dI4.x + 32 + qo);
    GLOAD8(gB1, xtb + dI4.y + 32 + qo);
    GLOAD8(gB2, xtb + dI4.z + 32 + qo);
    GLOAD8(gB3, xtb + dI4.w + 32 + qo);
    GLOAD16(bA0, bpb);
    GLOAD16(bA1, bpb + 512);
  }
  BARRIER_LGKM   // As[0] visible; 6 asm loads stay in flight

  // ---- steady loop: T = 0..69 ----
#pragma unroll 1
  for (int t = 0; t < 70; t += 2) {
    FITER_S(t,     0, gA0, gA1, gA2, gA3, gB0, gB1, gB2, gB3, bA0, bA1, bB0, bB1)
    FITER_S(t + 1, 1, gB0, gB1, gB2, gB3, gA0, gA1, gA2, gA3, bB0, bB1, bA0, bA1)
  }

  // ---- peeled T=70 (PAR=0): consume gB=G(71), bA=B(70); issue B(71)->bB ----
  {
    const unsigned short* bt_ = bpb + (size_t)71 * 8192;
    GLOAD16(bB0, bt_);
    GLOAD16(bB1, bt_ + 512);
    afr0 = *(const bf16x8*)&As[0][row][quad * 8];
    afr1 = *(const bf16x8*)&As[0][16 + row][quad * 8];
    afr2 = *(const bf16x8*)&As[0][32 + row][quad * 8];
    afr3 = *(const bf16x8*)&As[0][48 + row][quad * 8];
    WAITVM(4)
    bilin4p(gB0, gB1, gB2, gB3, dW4, &As[1][r][qo]);   // dW4 = tap 8 (set at T=63)
    WAITVM(2)
    MFMA8(afr0, afr1, afr2, afr3, bA0, bA1)
    BARRIER_LGKM
  }
  // ---- peeled T=71 (PAR=1): consume bB=B(71); no bilin ----
  {
    afr0 = *(const bf16x8*)&As[1][row][quad * 8];
    afr1 = *(const bf16x8*)&As[1][16 + row][quad * 8];
    afr2 = *(const bf16x8*)&As[1][32 + row][quad * 8];
    afr3 = *(const bf16x8*)&As[1][48 + row][quad * 8];
    WAITVM(0)
    MFMA8(afr0, afr1, afr2, afr3, bB0, bB1)
  }

  // ---- epilogue: add bias, store NCHW ----
#pragma unroll
  for (int j = 0; j < 2; ++j) {
    int o = wv * 32 + j * 16 + row;
    float bo = bias[o];
#pragma unroll
    for (int i = 0; i < 4; ++i) {
      int hw = hw0 + i * 16 + quad * 4;
      float4 v;
      v.x = acc[i][j][0] + bo;
      v.y = acc[i][j][1] + bo;
      v.z = acc[i][j][2] + bo;
      v.w = acc[i][j][3] + bo;
      *(float4*)(out + (((size_t)(b * COUT + o)) << 12) + hw) = v;
    }
  }
}

// ---------------- launch ----------------
extern "C" void kernel_launch(void* const* d_in, const int* in_sizes, int n_in,
                              void* d_out, int out_size, void* d_ws, size_t ws_size,
                              hipStream_t stream) {
  const float* x        = (const float*)d_in[0];
  const float* weight   = (const float*)d_in[1];
  const float* bias     = (const float*)d_in[2];
  const float* p_weight = (const float*)d_in[3];
  const float* p_bias   = (const float*)d_in[4];
  float* out = (float*)d_out;
  char* ws = (char*)d_ws;

  // workspace layout (bytes); total ~31 MB
  const size_t OFF_XT   = 0;                          //  8,388,608  bf16 NHWC x
  const size_t OFF_WB   = OFF_XT + 8388608;           //  1,179,648  bf16 WB2
  const size_t OFF_PW   = OFF_WB + 1179648;           //    147,456  bf16
  const size_t OFF_P    = OFF_PW + 147456;            // 16,777,216  fp32 partials
  const size_t OFF_ZP   = OFF_P + 16777216;           //      8,192  zeropage
  const size_t OFF_DIW  = OFF_ZP + 8192;              //  4,718,592  idx/weight table

  unsigned short* xt    = (unsigned short*)(ws + OFF_XT);
  unsigned short* WB    = (unsigned short*)(ws + OFF_WB);
  unsigned short* PWs   = (unsigned short*)(ws + OFF_PW);
  float* Pbuf           = (float*)(ws + OFF_P);
  unsigned short* zerop = (unsigned short*)(ws + OFF_ZP);
  int4* DIW             = (int4*)(ws + OFF_DIW);

  prep_and_transpose<<<4096 + 2592, 256, 0, stream>>>(x, weight, p_weight, xt, WB, PWs, zerop);
  offset_conv_sk<<<dim3(MTOT / 64, SPLITK), 256, 0, stream>>>(xt, PWs, zerop, Pbuf);
  index_prep<<<576, 256, 0, stream>>>(Pbuf, p_bias, DIW);
  fused_gemm<<<256, 512, 0, stream>>>(xt, DIW, WB, bias, out);
}